// Round 16
// baseline (165.201 us; speedup 1.0000x reference)
//
#include <hip/hip_runtime.h>
#include <hip/hip_bf16.h>

#define N_NODES 50000
#define N_PAD   50048   // 391 * 128
#define N_EDGES 150000
#define F 512
#define BM 128
#define BN 128
#define BK 64
#define NBLK 196        // ceil(50000/256)
#define NWG  1564       // 391 * 4 gemm blocks
#define DEGB 586        // ceil(150000/256)
#define WTB  1024       // F*F/256
#define XBB  12500      // N_NODES*F/8/256

typedef __attribute__((ext_vector_type(4))) float f32x4;
typedef __attribute__((ext_vector_type(4))) unsigned int u32x4;
typedef __attribute__((ext_vector_type(2))) unsigned int u32x2;

__device__ __forceinline__ unsigned short f2bf(float f) {
    unsigned int u = __float_as_uint(f);
    return (unsigned short)((u + 0x7fffu + ((u >> 16) & 1u)) >> 16);
}
__device__ __forceinline__ unsigned int pack2(float a, float b) {
    return (unsigned int)f2bf(a) | ((unsigned int)f2bf(b) << 16);
}
__device__ __forceinline__ void gload16(const void* g, void* l) {
    __builtin_amdgcn_global_load_lds(
        (const __attribute__((address_space(1))) unsigned int*)g,
        (__attribute__((address_space(3))) unsigned int*)l, 16, 0, 0);
}

// ---- fused: deg histograms | Wt transpose | xb = bf16(x) (unscaled) ----
__global__ void __launch_bounds__(256) crd_deg_wt_xb(const int* __restrict__ src,
                                                     const int* __restrict__ dst,
                                                     int* __restrict__ hist,
                                                     const float* __restrict__ W,
                                                     unsigned short* __restrict__ Wt,
                                                     const float* __restrict__ x,
                                                     unsigned short* __restrict__ xb,
                                                     int do_xb) {
    int b = blockIdx.x;
    if (b < DEGB) {
        int e = b * 256 + threadIdx.x;
        if (e < N_EDGES) {
            atomicAdd(&hist[src[e]], 1);
            atomicAdd(&hist[N_NODES + dst[e]], 1);
        }
    } else if (b < DEGB + WTB) {
        int idx = (b - DEGB) * 256 + threadIdx.x;
        int n = idx >> 9, k = idx & 511;
        Wt[idx] = f2bf(W[k * F + n]);
    } else if (do_xb) {
        size_t i = ((size_t)(b - DEGB - WTB) * 256 + threadIdx.x) * 8;
        f32x4 v0 = *(const f32x4*)(x + i);
        f32x4 v1 = *(const f32x4*)(x + i + 4);
        u32x4 w;
        w.x = pack2(v0.x, v0.y); w.y = pack2(v0.z, v0.w);
        w.z = pack2(v1.x, v1.y); w.w = pack2(v1.z, v1.w);
        *(u32x4*)(xb + i) = w;
    }
}

// ---- fused: norms (all 391 blocks) | per-block deg_in sums (blocks < NBLK) ----
__global__ void __launch_bounds__(256) crd_norm_bsum(const int* __restrict__ hist,
                                                     float* __restrict__ norms,
                                                     int* __restrict__ bsum) {
    __shared__ int s[256];
    int b = blockIdx.x, t = threadIdx.x;
    int i = b * 256 + t;
    if (i < 2 * N_NODES) {
        int d = hist[i];
        norms[i] = rsqrtf((float)(d > 0 ? d : 1));
    }
    if (b < NBLK) {
        s[t] = (i < N_NODES) ? hist[N_NODES + i] : 0;
        __syncthreads();
        #pragma unroll
        for (int o = 128; o > 0; o >>= 1) {
            if (t < o) s[t] += s[t + o];
            __syncthreads();
        }
        if (t == 0) bsum[b] = s[0];
    }
}

// ---- escan with inlined block-base (r15-proven) ----
__global__ void __launch_bounds__(256) crd_escan2(const int* __restrict__ hist_in,
                                                  const int* __restrict__ bsum,
                                                  int* __restrict__ off,
                                                  int* __restrict__ cursor) {
    __shared__ int sh[256];
    __shared__ int base_sh;
    const int b = blockIdx.x, t = threadIdx.x;
    sh[t] = (t < b) ? bsum[t] : 0;
    __syncthreads();
    #pragma unroll
    for (int o = 128; o > 0; o >>= 1) {
        if (t < o) sh[t] += sh[t + o];
        __syncthreads();
    }
    if (t == 0) base_sh = sh[0];
    __syncthreads();
    const int base = base_sh;
    __syncthreads();
    int i = b * 256 + t;
    int v = (i < N_NODES) ? hist_in[i] : 0;
    sh[t] = v;
    __syncthreads();
    #pragma unroll
    for (int d = 1; d < 256; d <<= 1) {
        int add = (t >= d) ? sh[t - d] : 0;
        __syncthreads();
        sh[t] += add;
        __syncthreads();
    }
    int excl = sh[t] - v + base;
    if (i < N_NODES) { off[i] = excl; cursor[i] = excl; }
    if (i == N_NODES - 1) off[N_NODES] = excl + v;
}

__global__ void __launch_bounds__(256) crd_place(const int* __restrict__ src,
                                                 const int* __restrict__ dst,
                                                 int* __restrict__ cursor,
                                                 int* __restrict__ sorted) {
    int e = blockIdx.x * 256 + threadIdx.x;
    if (e < N_EDGES) {
        int slot = atomicAdd(&cursor[dst[e]], 1);
        sorted[slot] = src[e];
    }
}

__device__ __forceinline__ void acc8s(float* a, u32x4 v, float ns) {
    a[0] += __uint_as_float(v.x << 16) * ns;
    a[1] += __uint_as_float(v.x & 0xffff0000u) * ns;
    a[2] += __uint_as_float(v.y << 16) * ns;
    a[3] += __uint_as_float(v.y & 0xffff0000u) * ns;
    a[4] += __uint_as_float(v.z << 16) * ns;
    a[5] += __uint_as_float(v.z & 0xffff0000u) * ns;
    a[6] += __uint_as_float(v.w << 16) * ns;
    a[7] += __uint_as_float(v.w & 0xffff0000u) * ns;
}

// ---- gather (bf16 x): 1 wave/node, u32x4 (16B = 8 bf16) per lane per edge.
// r3-proven body; norm_src applied in f32 accumulate (xb is unscaled).
__global__ void __launch_bounds__(256) crd_gather_bf(const unsigned short* __restrict__ xb,
                                                     const int* __restrict__ sorted,
                                                     const int* __restrict__ off,
                                                     const float* __restrict__ norms,
                                                     unsigned short* __restrict__ aggb) {
    int wid = (blockIdx.x * 256 + threadIdx.x) >> 6;
    int lane = threadIdx.x & 63;
    if (wid >= N_PAD) return;
    float a[8] = {0.f,0.f,0.f,0.f,0.f,0.f,0.f,0.f};
    float b[8] = {0.f,0.f,0.f,0.f,0.f,0.f,0.f,0.f};
    if (wid < N_NODES) {
        int e0 = off[wid], e1 = off[wid + 1];
        int e = e0;
        for (; e + 1 < e1; e += 2) {
            int s0 = sorted[e], s1 = sorted[e + 1];
            float ns0 = norms[s0], ns1 = norms[s1];
            u32x4 v0 = *(const u32x4*)(xb + (size_t)s0 * F + lane * 8);
            u32x4 v1 = *(const u32x4*)(xb + (size_t)s1 * F + lane * 8);
            acc8s(a, v0, ns0);
            acc8s(b, v1, ns1);
        }
        if (e < e1) {
            int s = sorted[e];
            u32x4 v = *(const u32x4*)(xb + (size_t)s * F + lane * 8);
            acc8s(a, v, norms[s]);
        }
        float nd = norms[N_NODES + wid];
        #pragma unroll
        for (int j = 0; j < 8; ++j) a[j] = (a[j] + b[j]) * nd;
    }
    u32x4 w;
    w.x = pack2(a[0], a[1]); w.y = pack2(a[2], a[3]);
    w.z = pack2(a[4], a[5]); w.w = pack2(a[6], a[7]);
    *(u32x4*)(aggb + (size_t)wid * F + lane * 8) = w;
}

// ---- fallback gather (f32 x, r15-proven): 2 waves/node ----
__global__ void __launch_bounds__(256) crd_gather_f32(const float* __restrict__ x,
                                                      const int* __restrict__ sorted,
                                                      const int* __restrict__ off,
                                                      const float* __restrict__ norms,
                                                      unsigned short* __restrict__ aggb) {
    int gw = (blockIdx.x * 256 + threadIdx.x) >> 6;
    int lane = threadIdx.x & 63;
    int wid = gw >> 1, half = gw & 1;
    if (wid >= N_PAD) return;
    f32x4 a = {0.f,0.f,0.f,0.f}, b = a;
    if (wid < N_NODES) {
        int e0 = off[wid], e1 = off[wid + 1];
        const float* xh = x + half * 256;
        int e = e0;
        for (; e + 1 < e1; e += 2) {
            int s0 = sorted[e], s1 = sorted[e + 1];
            float ns0 = norms[s0], ns1 = norms[s1];
            a += ((const f32x4*)(xh + (size_t)s0 * F))[lane] * ns0;
            b += ((const f32x4*)(xh + (size_t)s1 * F))[lane] * ns1;
        }
        if (e < e1) {
            int s = sorted[e];
            a += ((const f32x4*)(xh + (size_t)s * F))[lane] * norms[s];
        }
        float nd = norms[N_NODES + wid];
        a = (a + b) * nd;
    }
    u32x2 w;
    w.x = pack2(a.x, a.y); w.y = pack2(a.z, a.w);
    *(u32x2*)(aggb + (size_t)wid * F + half * 256 + lane * 4) = w;
}

// ---- out = relu(aggb @ W + b): r7/r10/r15-proven GEMM (unchanged) ----
// Swapped-operand MFMA: D[n][m]; lane m = l&15, n-quad = (l>>4)*4.
__global__ void __launch_bounds__(256, 4) crd_gemm(const unsigned short* __restrict__ aggb,
                                                   const unsigned short* __restrict__ Wt,
                                                   const float* __restrict__ bias,
                                                   float* __restrict__ out) {
    __shared__ __align__(16) unsigned short lA[8 * BM * 8];   // 16 KB
    __shared__ __align__(16) unsigned short lB[8 * BN * 8];   // 16 KB
    const int tid = threadIdx.x;
    int bid = blockIdx.x;
    int xcd = bid & 7, lid = bid >> 3;
    int swz = (xcd < 4 ? xcd * 196 : 784 + (xcd - 4) * 195) + lid;
    const int rowbase = (swz >> 2) * BM;
    const int nbase = (swz & 3) * BN;
    const int lane = tid & 63;
    const int wave = tid >> 6;
    const int wm = wave >> 1, wn = wave & 1;
    const int g = lane >> 4, r = lane & 15;

    f32x4 acc[4][4];
    #pragma unroll
    for (int i = 0; i < 4; ++i)
        #pragma unroll
        for (int j = 0; j < 4; ++j) acc[i][j] = (f32x4){0.f, 0.f, 0.f, 0.f};

    for (int ks = 0; ks < F / BK; ++ks) {
        #pragma unroll
        for (int j = 0; j < 4; ++j) {
            int gg = (wave * 4 + j) * 64 + lane;
            int k8 = gg >> 7, row = gg & 127;
            gload16(aggb + (size_t)(rowbase + row) * F + ks * BK + k8 * 8,
                    &lA[(size_t)(wave * 4 + j) * 64 * 8]);
        }
        #pragma unroll
        for (int j = 0; j < 4; ++j) {
            int gg = (wave * 4 + j) * 64 + lane;
            int k8 = gg >> 7, n = gg & 127;
            gload16(Wt + (size_t)(nbase + n) * F + ks * BK + k8 * 8,
                    &lB[(size_t)(wave * 4 + j) * 64 * 8]);
        }
        __syncthreads();
        #pragma unroll
        for (int kk = 0; kk < 2; ++kk) {
            int k8 = kk * 4 + g;
            u32x4 af[4], bfr[4];
            #pragma unroll
            for (int mi = 0; mi < 4; ++mi)
                af[mi] = *(const u32x4*)&lA[(k8 * BM + wm * 64 + mi * 16 + r) * 8];
            #pragma unroll
            for (int ni = 0; ni < 4; ++ni)
                bfr[ni] = *(const u32x4*)&lB[(k8 * BN + wn * 64 + ni * 16 + r) * 8];
            #pragma unroll
            for (int mi = 0; mi < 4; ++mi)
                #pragma unroll
                for (int ni = 0; ni < 4; ++ni)
                    asm("v_mfma_f32_16x16x32_bf16 %0, %1, %2, %0"
                        : "+v"(acc[mi][ni]) : "v"(bfr[ni]), "v"(af[mi]));   // swapped
        }
        __syncthreads();
    }
    #pragma unroll
    for (int mi = 0; mi < 4; ++mi) {
        int row = rowbase + wm * 64 + mi * 16 + r;
        if (row < N_NODES) {
            #pragma unroll
            for (int ni = 0; ni < 4; ++ni) {
                int c0 = nbase + wn * 64 + ni * 16 + g * 4;
                f32x4 bv = *(const f32x4*)(bias + c0);
                f32x4 v = acc[mi][ni] + bv;
                v.x = fmaxf(v.x, 0.f); v.y = fmaxf(v.y, 0.f);
                v.z = fmaxf(v.z, 0.f); v.w = fmaxf(v.w, 0.f);
                *(f32x4*)(out + (size_t)row * F + c0) = v;
            }
        }
    }
}

extern "C" void kernel_launch(void* const* d_in, const int* in_sizes, int n_in,
                              void* d_out, int out_size, void* d_ws, size_t ws_size,
                              hipStream_t stream) {
    const float* x = (const float*)d_in[0];
    const int* src = (const int*)d_in[1];
    const int* dst = (const int*)d_in[2];
    const float* W = (const float*)d_in[3];
    const float* bias = (const float*)d_in[4];
    float* out = (float*)d_out;

    float* norms = (float*)d_ws;                                // 2N f32
    int* hist = (int*)(norms + 2 * N_NODES);                    // 2N int
    int* off = hist + 2 * N_NODES;                              // N+1 int
    int* cursor = off + N_NODES + 1;                            // N int
    int* sorted = cursor + N_NODES;                             // E int
    int* bsum = sorted + N_EDGES;                               // NBLK int
    unsigned short* Wt = (unsigned short*)
        (((uintptr_t)(bsum + NBLK) + 63) & ~(uintptr_t)63);     // F*F bf16
    unsigned short* aggb = Wt + (size_t)F * F;                  // N_PAD*F bf16
    unsigned short* xb = aggb + (size_t)N_PAD * F;              // N_NODES*F bf16
    size_t need_min = (size_t)((char*)xb - (char*)d_ws);
    size_t need_bf = (size_t)((char*)(xb + (size_t)N_NODES * F) - (char*)d_ws);
    if (ws_size < need_min) {
        hipMemsetAsync(d_out, 0, (size_t)out_size * sizeof(float), stream);
        return;
    }
    const int use_bf = (ws_size >= need_bf) ? 1 : 0;

    hipMemsetAsync(hist, 0, 2 * N_NODES * sizeof(int), stream);
    int grid0 = DEGB + WTB + (use_bf ? XBB : 0);
    crd_deg_wt_xb<<<grid0, 256, 0, stream>>>(src, dst, hist, W, Wt, x, xb, use_bf);
    crd_norm_bsum<<<391, 256, 0, stream>>>(hist, norms, bsum);
    crd_escan2<<<NBLK, 256, 0, stream>>>(hist + N_NODES, bsum, off, cursor);
    crd_place<<<(N_EDGES + 255) / 256, 256, 0, stream>>>(src, dst, cursor, sorted);
    if (use_bf) {
        crd_gather_bf<<<N_PAD / 4, 256, 0, stream>>>(xb, sorted, off, norms, aggb);
    } else {
        crd_gather_f32<<<N_PAD / 2, 256, 0, stream>>>(x, sorted, off, norms, aggb);
    }
    crd_gemm<<<NWG, 256, 0, stream>>>(aggb, Wt, bias, out);
}

// Round 17
// 159.561 us; speedup vs baseline: 1.0353x; 1.0353x over previous
//
#include <hip/hip_runtime.h>
#include <hip/hip_bf16.h>

#define N_NODES 50000
#define N_PAD   50048   // 391 * 128
#define N_EDGES 150000
#define F 512
#define BM 128
#define BN 128
#define BK 64
#define NBLK 196        // ceil(50000/256)
#define NWG  1564       // 391 * 4 gemm blocks
#define DEGB 586        // ceil(150000/256)

typedef __attribute__((ext_vector_type(4))) float f32x4;
typedef __attribute__((ext_vector_type(4))) unsigned int u32x4;
typedef __attribute__((ext_vector_type(2))) unsigned int u32x2;

__device__ __forceinline__ unsigned short f2bf(float f) {
    unsigned int u = __float_as_uint(f);
    return (unsigned short)((u + 0x7fffu + ((u >> 16) & 1u)) >> 16);
}
__device__ __forceinline__ unsigned int pack2(float a, float b) {
    return (unsigned int)f2bf(a) | ((unsigned int)f2bf(b) << 16);
}
__device__ __forceinline__ void gload16(const void* g, void* l) {
    __builtin_amdgcn_global_load_lds(
        (const __attribute__((address_space(1))) unsigned int*)g,
        (__attribute__((address_space(3))) unsigned int*)l, 16, 0, 0);
}

// ---- fused: degree histograms (blocks < DEGB) | Wt transpose (rest) ----
__global__ void __launch_bounds__(256) crd_deg_wt(const int* __restrict__ src,
                                                  const int* __restrict__ dst,
                                                  int* __restrict__ hist,
                                                  const float* __restrict__ W,
                                                  unsigned short* __restrict__ Wt) {
    int b = blockIdx.x;
    if (b < DEGB) {
        int e = b * 256 + threadIdx.x;
        if (e < N_EDGES) {
            atomicAdd(&hist[src[e]], 1);
            atomicAdd(&hist[N_NODES + dst[e]], 1);
        }
    } else {
        int idx = (b - DEGB) * 256 + threadIdx.x;   // 1024 blocks, F*F elems
        int n = idx >> 9, k = idx & 511;
        Wt[idx] = f2bf(W[k * F + n]);
    }
}

// ---- fused: norms (all 391 blocks) | per-block deg_in sums (blocks < NBLK) ----
__global__ void __launch_bounds__(256) crd_norm_bsum(const int* __restrict__ hist,
                                                     float* __restrict__ norms,
                                                     int* __restrict__ bsum) {
    __shared__ int s[256];
    int b = blockIdx.x, t = threadIdx.x;
    int i = b * 256 + t;
    if (i < 2 * N_NODES) {
        int d = hist[i];
        norms[i] = rsqrtf((float)(d > 0 ? d : 1));
    }
    if (b < NBLK) {
        s[t] = (i < N_NODES) ? hist[N_NODES + i] : 0;
        __syncthreads();
        #pragma unroll
        for (int o = 128; o > 0; o >>= 1) {
            if (t < o) s[t] += s[t + o];
            __syncthreads();
        }
        if (t == 0) bsum[b] = s[0];
    }
}

// ---- escan with inlined block-base: base = sum(bsum[0..b)), then chunk scan ----
__global__ void __launch_bounds__(256) crd_escan2(const int* __restrict__ hist_in,
                                                  const int* __restrict__ bsum,
                                                  int* __restrict__ off,
                                                  int* __restrict__ cursor) {
    __shared__ int sh[256];
    __shared__ int base_sh;
    const int b = blockIdx.x, t = threadIdx.x;
    // base = exclusive prefix over chunk sums (b <= 195 < 256: one reduction)
    sh[t] = (t < b) ? bsum[t] : 0;
    __syncthreads();
    #pragma unroll
    for (int o = 128; o > 0; o >>= 1) {
        if (t < o) sh[t] += sh[t + o];
        __syncthreads();
    }
    if (t == 0) base_sh = sh[0];
    __syncthreads();
    const int base = base_sh;
    __syncthreads();                       // sh reuse safe
    // per-chunk inclusive scan (r10-proven)
    int i = b * 256 + t;
    int v = (i < N_NODES) ? hist_in[i] : 0;
    sh[t] = v;
    __syncthreads();
    #pragma unroll
    for (int d = 1; d < 256; d <<= 1) {
        int add = (t >= d) ? sh[t - d] : 0;
        __syncthreads();
        sh[t] += add;
        __syncthreads();
    }
    int excl = sh[t] - v + base;
    if (i < N_NODES) { off[i] = excl; cursor[i] = excl; }
    if (i == N_NODES - 1) off[N_NODES] = excl + v;
}

__global__ void __launch_bounds__(256) crd_place(const int* __restrict__ src,
                                                 const int* __restrict__ dst,
                                                 int* __restrict__ cursor,
                                                 int* __restrict__ sorted) {
    int e = blockIdx.x * 256 + threadIdx.x;
    if (e < N_EDGES) {
        int slot = atomicAdd(&cursor[dst[e]], 1);
        sorted[slot] = src[e];
    }
}

// ---- gather: 2 waves per dst node, each owns a 256-float half-row (r10-proven) ----
__global__ void __launch_bounds__(256) crd_gather(const float* __restrict__ x,
                                                  const int* __restrict__ sorted,
                                                  const int* __restrict__ off,
                                                  const float* __restrict__ norms,
                                                  unsigned short* __restrict__ aggb) {
    int gw = (blockIdx.x * 256 + threadIdx.x) >> 6;   // global wave id
    int lane = threadIdx.x & 63;
    int wid = gw >> 1, half = gw & 1;
    if (wid >= N_PAD) return;
    f32x4 a = {0.f,0.f,0.f,0.f}, b = a;
    if (wid < N_NODES) {
        int e0 = off[wid], e1 = off[wid + 1];
        const float* xh = x + half * 256;
        int e = e0;
        for (; e + 1 < e1; e += 2) {                  // 2-edge unroll (ILP)
            int s0 = sorted[e], s1 = sorted[e + 1];
            float ns0 = norms[s0], ns1 = norms[s1];
            a += ((const f32x4*)(xh + (size_t)s0 * F))[lane] * ns0;
            b += ((const f32x4*)(xh + (size_t)s1 * F))[lane] * ns1;
        }
        if (e < e1) {
            int s = sorted[e];
            a += ((const f32x4*)(xh + (size_t)s * F))[lane] * norms[s];
        }
        float nd = norms[N_NODES + wid];
        a = (a + b) * nd;
    }
    u32x2 w;
    w.x = pack2(a.x, a.y); w.y = pack2(a.z, a.w);
    *(u32x2*)(aggb + (size_t)wid * F + half * 256 + lane * 4) = w;
}

// ---- out = relu(aggb @ W + b): r7/r10-proven GEMM, 4 blocks/CU residency ----
// Swapped-operand MFMA: D[n][m]; lane m = l&15, n-quad = (l>>4)*4.
__global__ void __launch_bounds__(256, 4) crd_gemm(const unsigned short* __restrict__ aggb,
                                                   const unsigned short* __restrict__ Wt,
                                                   const float* __restrict__ bias,
                                                   float* __restrict__ out) {
    __shared__ __align__(16) unsigned short lA[8 * BM * 8];   // 16 KB
    __shared__ __align__(16) unsigned short lB[8 * BN * 8];   // 16 KB
    const int tid = threadIdx.x;
    // XCD-bijective swizzle (r4/r7-proven: FETCH 104->29 MB)
    int bid = blockIdx.x;
    int xcd = bid & 7, lid = bid >> 3;
    int swz = (xcd < 4 ? xcd * 196 : 784 + (xcd - 4) * 195) + lid;
    const int rowbase = (swz >> 2) * BM;
    const int nbase = (swz & 3) * BN;
    const int lane = tid & 63;
    const int wave = tid >> 6;
    const int wm = wave >> 1, wn = wave & 1;
    const int g = lane >> 4, r = lane & 15;

    f32x4 acc[4][4];
    #pragma unroll
    for (int i = 0; i < 4; ++i)
        #pragma unroll
        for (int j = 0; j < 4; ++j) acc[i][j] = (f32x4){0.f, 0.f, 0.f, 0.f};

    for (int ks = 0; ks < F / BK; ++ks) {
        #pragma unroll
        for (int j = 0; j < 4; ++j) {
            int gg = (wave * 4 + j) * 64 + lane;
            int k8 = gg >> 7, row = gg & 127;
            gload16(aggb + (size_t)(rowbase + row) * F + ks * BK + k8 * 8,
                    &lA[(size_t)(wave * 4 + j) * 64 * 8]);
        }
        #pragma unroll
        for (int j = 0; j < 4; ++j) {
            int gg = (wave * 4 + j) * 64 + lane;
            int k8 = gg >> 7, n = gg & 127;
            gload16(Wt + (size_t)(nbase + n) * F + ks * BK + k8 * 8,
                    &lB[(size_t)(wave * 4 + j) * 64 * 8]);
        }
        __syncthreads();
        #pragma unroll
        for (int kk = 0; kk < 2; ++kk) {
            int k8 = kk * 4 + g;
            u32x4 af[4], bfr[4];
            #pragma unroll
            for (int mi = 0; mi < 4; ++mi)
                af[mi] = *(const u32x4*)&lA[(k8 * BM + wm * 64 + mi * 16 + r) * 8];
            #pragma unroll
            for (int ni = 0; ni < 4; ++ni)
                bfr[ni] = *(const u32x4*)&lB[(k8 * BN + wn * 64 + ni * 16 + r) * 8];
            #pragma unroll
            for (int mi = 0; mi < 4; ++mi)
                #pragma unroll
                for (int ni = 0; ni < 4; ++ni)
                    asm("v_mfma_f32_16x16x32_bf16 %0, %1, %2, %0"
                        : "+v"(acc[mi][ni]) : "v"(bfr[ni]), "v"(af[mi]));   // swapped
        }
        __syncthreads();
    }
    #pragma unroll
    for (int mi = 0; mi < 4; ++mi) {
        int row = rowbase + wm * 64 + mi * 16 + r;
        if (row < N_NODES) {
            #pragma unroll
            for (int ni = 0; ni < 4; ++ni) {
                int c0 = nbase + wn * 64 + ni * 16 + g * 4;
                f32x4 bv = *(const f32x4*)(bias + c0);
                f32x4 v = acc[mi][ni] + bv;
                v.x = fmaxf(v.x, 0.f); v.y = fmaxf(v.y, 0.f);
                v.z = fmaxf(v.z, 0.f); v.w = fmaxf(v.w, 0.f);
                *(f32x4*)(out + (size_t)row * F + c0) = v;
            }
        }
    }
}

extern "C" void kernel_launch(void* const* d_in, const int* in_sizes, int n_in,
                              void* d_out, int out_size, void* d_ws, size_t ws_size,
                              hipStream_t stream) {
    const float* x = (const float*)d_in[0];
    const int* src = (const int*)d_in[1];
    const int* dst = (const int*)d_in[2];
    const float* W = (const float*)d_in[3];
    const float* bias = (const float*)d_in[4];
    float* out = (float*)d_out;

    float* norms = (float*)d_ws;                                // 2N f32
    int* hist = (int*)(norms + 2 * N_NODES);                    // 2N int
    int* off = hist + 2 * N_NODES;                              // N+1 int
    int* cursor = off + N_NODES + 1;                            // N int
    int* sorted = cursor + N_NODES;                             // E int
    int* bsum = sorted + N_EDGES;                               // NBLK int
    unsigned short* Wt = (unsigned short*)
        (((uintptr_t)(bsum + NBLK) + 63) & ~(uintptr_t)63);     // F*F bf16
    unsigned short* aggb = Wt + (size_t)F * F;                  // N_PAD*F bf16
    size_t need = (size_t)((char*)(aggb + (size_t)N_PAD * F) - (char*)d_ws);
    if (ws_size < need) {
        hipMemsetAsync(d_out, 0, (size_t)out_size * sizeof(float), stream);
        return;
    }

    hipMemsetAsync(hist, 0, 2 * N_NODES * sizeof(int), stream);
    crd_deg_wt<<<DEGB + (F * F) / 256, 256, 0, stream>>>(src, dst, hist, W, Wt);
    crd_norm_bsum<<<391, 256, 0, stream>>>(hist, norms, bsum);
    crd_escan2<<<NBLK, 256, 0, stream>>>(hist + N_NODES, bsum, off, cursor);
    crd_place<<<(N_EDGES + 255) / 256, 256, 0, stream>>>(src, dst, cursor, sorted);
    crd_gather<<<N_PAD / 2, 256, 0, stream>>>(x, sorted, off, norms, aggb);
    crd_gemm<<<NWG, 256, 0, stream>>>(aggb, Wt, bias, out);
}